// Round 1
// baseline (3456.845 us; speedup 1.0000x reference)
//
#include <hip/hip_runtime.h>

#define B_SZ    2
#define LSEQ    2048
#define DMODEL  768
#define DINNER  1536
#define NHEADS  24
#define HD      64
#define CDPH    192
#define CONVDIM 4608
#define DIP     6168
#define MROWS   (B_SZ*LSEQ)   // 4096

__device__ __forceinline__ float siluf(float x) {
    return x / (1.0f + __expf(-x));
}

// C[m,n] = sum_k A[m,k] * B[n,k];  A:[M,K] row-major, B:[N,K] row-major.
// BM=128, BN=64, BK=16, 256 threads, 8x4 micro-tile.
__global__ __launch_bounds__(256) void gemm_nt_f32(
    const float* __restrict__ A, const float* __restrict__ B,
    float* __restrict__ C, int M, int N, int K)
{
    __shared__ __attribute__((aligned(16))) float As[16][132];
    __shared__ __attribute__((aligned(16))) float Bs[16][68];
    const int ntn = (N + 63) >> 6;
    const int bm = blockIdx.x / ntn;
    const int bn = blockIdx.x - bm * ntn;
    const int m0 = bm << 7, n0 = bn << 6;
    const int tid = threadIdx.x;
    const int tx = tid & 15, ty = tid >> 4;

    float acc[8][4];
#pragma unroll
    for (int i = 0; i < 8; ++i)
#pragma unroll
        for (int j = 0; j < 4; ++j) acc[i][j] = 0.f;

    const int ar = tid >> 1;          // 0..127
    const int ac = (tid & 1) << 3;    // 0 or 8
    const int br = tid >> 2;          // 0..63
    const int bc = (tid & 3) << 2;    // 0,4,8,12
    const float* Ap = A + (size_t)(m0 + ar) * K + ac;
    const bool bval = (n0 + br) < N;
    const float* Bp = B + (size_t)(n0 + br) * K + bc;

    for (int k0 = 0; k0 < K; k0 += 16) {
        const float4 a0 = *(const float4*)(Ap + k0);
        const float4 a1 = *(const float4*)(Ap + k0 + 4);
        float4 bv = make_float4(0.f, 0.f, 0.f, 0.f);
        if (bval) bv = *(const float4*)(Bp + k0);
        __syncthreads();
        As[ac + 0][ar] = a0.x; As[ac + 1][ar] = a0.y;
        As[ac + 2][ar] = a0.z; As[ac + 3][ar] = a0.w;
        As[ac + 4][ar] = a1.x; As[ac + 5][ar] = a1.y;
        As[ac + 6][ar] = a1.z; As[ac + 7][ar] = a1.w;
        Bs[bc + 0][br] = bv.x; Bs[bc + 1][br] = bv.y;
        Bs[bc + 2][br] = bv.z; Bs[bc + 3][br] = bv.w;
        __syncthreads();
#pragma unroll
        for (int k = 0; k < 16; ++k) {
            const float4 av0 = *(const float4*)&As[k][ty << 3];
            const float4 av1 = *(const float4*)&As[k][(ty << 3) + 4];
            const float4 bvv = *(const float4*)&Bs[k][tx << 2];
            const float aa[8] = {av0.x, av0.y, av0.z, av0.w,
                                 av1.x, av1.y, av1.z, av1.w};
            const float bb[4] = {bvv.x, bvv.y, bvv.z, bvv.w};
#pragma unroll
            for (int i = 0; i < 8; ++i)
#pragma unroll
                for (int j = 0; j < 4; ++j)
                    acc[i][j] = fmaf(aa[i], bb[j], acc[i][j]);
        }
    }
#pragma unroll
    for (int i = 0; i < 8; ++i) {
        const int m = m0 + (ty << 3) + i;
        float* Cr = C + (size_t)m * N + n0 + (tx << 2);
#pragma unroll
        for (int j = 0; j < 4; ++j)
            if (n0 + (tx << 2) + j < N) Cr[j] = acc[i][j];
    }
}

// One block per (b,h): 4 waves. Fused depthwise conv (register history) +
// nonlinear recurrence + y*silu(z) gating.
__global__ __launch_bounds__(256) void mamba_scan(
    const float* __restrict__ zx,      // [4096, DIP]
    const float* __restrict__ conv_w,  // [4608, 4]
    const float* __restrict__ conv_b,  // [4608]
    const float* __restrict__ R_x,     // [24,64,64]
    const float* __restrict__ R_B,
    const float* __restrict__ R_C,
    const float* __restrict__ R_dt,    // [24,64]
    const float* __restrict__ dt_bias, // [24]
    const float* __restrict__ A_log,   // [24]
    const float* __restrict__ Dvec,    // [24,64]
    float* __restrict__ yz)            // [4096, 1536]
{
    const int b = blockIdx.x / NHEADS;
    const int h = blockIdx.x % NHEADS;
    const int tid = threadIdx.x;
    const int w = tid >> 6;
    const int lane = tid & 63;

    __shared__ __attribute__((aligned(16))) float y_lds[64];
    __shared__ __attribute__((aligned(16))) float px[4][64];
    __shared__ __attribute__((aligned(16))) float pBb[4][64];
    __shared__ __attribute__((aligned(16))) float pCc[4][64];
    __shared__ __attribute__((aligned(16))) float py[4][64];
    __shared__ __attribute__((aligned(16))) float xl[64];
    __shared__ __attribute__((aligned(16))) float Bml[64];
    __shared__ __attribute__((aligned(16))) float Cml[64];
    __shared__ float pdt[4];
    __shared__ float sc[2];

    // R fragments in registers: wave w covers q in [16w, 16w+16)
    float Rx[16], Rb[16], Rc[16], Rdw[16];
    {
        const size_t rowoff = ((size_t)h * 64 + lane) * 64 + w * 16;
#pragma unroll
        for (int j = 0; j < 16; j += 4) {
            const float4 v = *(const float4*)(R_x + rowoff + j);
            Rx[j] = v.x; Rx[j + 1] = v.y; Rx[j + 2] = v.z; Rx[j + 3] = v.w;
        }
#pragma unroll
        for (int j = 0; j < 16; j += 4) {
            const float4 v = *(const float4*)(R_B + rowoff + j);
            Rb[j] = v.x; Rb[j + 1] = v.y; Rb[j + 2] = v.z; Rb[j + 3] = v.w;
        }
#pragma unroll
        for (int j = 0; j < 16; j += 4) {
            const float4 v = *(const float4*)(R_C + rowoff + j);
            Rc[j] = v.x; Rc[j + 1] = v.y; Rc[j + 2] = v.z; Rc[j + 3] = v.w;
        }
#pragma unroll
        for (int j = 0; j < 16; j += 4) {
            const float4 v = *(const float4*)(R_dt + h * 64 + w * 16 + j);
            Rdw[j] = v.x; Rdw[j + 1] = v.y; Rdw[j + 2] = v.z; Rdw[j + 3] = v.w;
        }
    }
    const float Aval = -__expf(A_log[h]);
    const float bias = dt_bias[h];
    const float dval = Dvec[h * 64 + lane];

    // depthwise conv: waves 0..2 own channel ch = w*64+lane (0..191)
    float cw0 = 0.f, cw1 = 0.f, cw2 = 0.f, cw3 = 0.f, cb = 0.f;
    float hh0 = 0.f, hh1 = 0.f, hh2 = 0.f;
    const int ch = w * 64 + lane;
    if (w < 3) {
        const float* cwp = conv_w + ((size_t)h * CDPH + ch) * 4;
        cw0 = cwp[0]; cw1 = cwp[1]; cw2 = cwp[2]; cw3 = cwp[3];
        cb = conv_b[h * CDPH + ch];
    }

    const float* xbc = zx + (size_t)b * LSEQ * DIP + DINNER + h * CDPH;
    const float* zb  = zx + (size_t)b * LSEQ * DIP + h * HD;
    const float* dtr = zx + (size_t)b * LSEQ * DIP + DINNER + CONVDIM + h;
    float* yzb = yz + (size_t)b * LSEQ * DINNER + h * HD;

    float st[16];
#pragma unroll
    for (int j = 0; j < 16; ++j) st[j] = 0.f;

    if (tid < 64) y_lds[tid] = 0.f;
    __syncthreads();

    float v_cur = 0.f, z_cur = 0.f, dtr_cur = 0.f;
    if (w < 3) v_cur = xbc[ch];
    else { z_cur = zb[lane]; if (lane == 0) dtr_cur = dtr[0]; }

    for (int t = 0; t < LSEQ; ++t) {
        // prefetch t+1 (clamped) — hides HBM/L2 latency under compute
        const size_t roff = (size_t)((t + 1 < LSEQ) ? t + 1 : t) * DIP;
        float v_nxt = 0.f, z_nxt = 0.f, dtr_nxt = 0.f;
        if (w < 3) v_nxt = xbc[roff + ch];
        else { z_nxt = zb[roff + lane]; if (lane == 0) dtr_nxt = dtr[roff]; }

        // ---- phase A: partial matvecs over this wave's q-window ----
        const float4 y0 = *(const float4*)&y_lds[w * 16];
        const float4 y1 = *(const float4*)&y_lds[w * 16 + 4];
        const float4 y2 = *(const float4*)&y_lds[w * 16 + 8];
        const float4 y3 = *(const float4*)&y_lds[w * 16 + 12];
        const float yq[16] = {y0.x, y0.y, y0.z, y0.w, y1.x, y1.y, y1.z, y1.w,
                              y2.x, y2.y, y2.z, y2.w, y3.x, y3.y, y3.z, y3.w};
        float ax = 0.f, ab = 0.f, acv = 0.f, ad = 0.f;
#pragma unroll
        for (int j = 0; j < 16; ++j) {
            ax  = fmaf(Rx[j],  yq[j], ax);
            ab  = fmaf(Rb[j],  yq[j], ab);
            acv = fmaf(Rc[j],  yq[j], acv);
            ad  = fmaf(Rdw[j], yq[j], ad);
        }
        px[w][lane] = ax; pBb[w][lane] = ab; pCc[w][lane] = acv;
        if (lane == 0) pdt[w] = ad;
        // conv output for this thread's channel (register-only)
        float xc = 0.f;
        if (w < 3) {
            xc = cb + cw0 * hh0 + cw1 * hh1 + cw2 * hh2 + cw3 * v_cur;
            hh0 = hh1; hh1 = hh2; hh2 = v_cur;
        }
        __syncthreads();  // 1

        // ---- reduce + silu ----
        if (w == 0) {
            const float v = xc + px[0][lane] + px[1][lane] + px[2][lane] + px[3][lane];
            xl[lane] = siluf(v);
        } else if (w == 1) {
            const float v = xc + pBb[0][lane] + pBb[1][lane] + pBb[2][lane] + pBb[3][lane];
            Bml[lane] = siluf(v);
        } else if (w == 2) {
            const float v = xc + pCc[0][lane] + pCc[1][lane] + pCc[2][lane] + pCc[3][lane];
            Cml[lane] = siluf(v);
        } else if (lane == 0) {
            const float dv = dtr_cur + pdt[0] + pdt[1] + pdt[2] + pdt[3] + bias;
            const float dtv = (dv > 20.f) ? dv : log1pf(__expf(dv));
            sc[0] = dtv;
            sc[1] = __expf(dtv * Aval);
        }
        __syncthreads();  // 2

        // ---- phase B: state update; lane p owns state[p][16w..16w+16) ----
        const float dtv = sc[0], dAv = sc[1];
        const float xme = xl[lane];
        const float kx = dtv * xme;
        const float4 bm0 = *(const float4*)&Bml[w * 16];
        const float4 bm1 = *(const float4*)&Bml[w * 16 + 4];
        const float4 bm2 = *(const float4*)&Bml[w * 16 + 8];
        const float4 bm3 = *(const float4*)&Bml[w * 16 + 12];
        const float4 cm0 = *(const float4*)&Cml[w * 16];
        const float4 cm1 = *(const float4*)&Cml[w * 16 + 4];
        const float4 cm2 = *(const float4*)&Cml[w * 16 + 8];
        const float4 cm3 = *(const float4*)&Cml[w * 16 + 12];
        const float bmv[16] = {bm0.x, bm0.y, bm0.z, bm0.w, bm1.x, bm1.y, bm1.z, bm1.w,
                               bm2.x, bm2.y, bm2.z, bm2.w, bm3.x, bm3.y, bm3.z, bm3.w};
        const float cmv[16] = {cm0.x, cm0.y, cm0.z, cm0.w, cm1.x, cm1.y, cm1.z, cm1.w,
                               cm2.x, cm2.y, cm2.z, cm2.w, cm3.x, cm3.y, cm3.z, cm3.w};
        float yp = 0.f;
#pragma unroll
        for (int j = 0; j < 16; ++j) {
            st[j] = fmaf(st[j], dAv, kx * bmv[j]);
            yp = fmaf(st[j], cmv[j], yp);
        }
        py[w][lane] = yp;
        __syncthreads();  // 3

        if (w == 3) {
            const float yn = py[0][lane] + py[1][lane] + py[2][lane] + py[3][lane]
                           + dval * xme;
            y_lds[lane] = yn;
            yzb[(size_t)t * DINNER + lane] = yn * siluf(z_cur);
        }
        __syncthreads();  // 4

        v_cur = v_nxt; z_cur = z_nxt; dtr_cur = dtr_nxt;
    }
}

extern "C" void kernel_launch(void* const* d_in, const int* in_sizes, int n_in,
                              void* d_out, int out_size, void* d_ws, size_t ws_size,
                              hipStream_t stream) {
    const float* u       = (const float*)d_in[0];
    const float* W_in    = (const float*)d_in[1];
    const float* conv_w  = (const float*)d_in[2];
    const float* conv_b  = (const float*)d_in[3];
    const float* R_x     = (const float*)d_in[4];
    const float* R_B     = (const float*)d_in[5];
    const float* R_C     = (const float*)d_in[6];
    const float* R_dt    = (const float*)d_in[7];
    const float* dt_bias = (const float*)d_in[8];
    const float* A_log   = (const float*)d_in[9];
    const float* Dv      = (const float*)d_in[10];
    const float* W_out   = (const float*)d_in[11];
    float* out = (float*)d_out;

    float* zx = (float*)d_ws;                      // [4096, 6168]
    float* yz = zx + (size_t)MROWS * DIP;          // [4096, 1536]

    {   // in-projection
        const int M = MROWS, N = DIP, K = DMODEL;
        const int grid = (M / 128) * ((N + 63) / 64);
        gemm_nt_f32<<<grid, 256, 0, stream>>>(u, W_in, zx, M, N, K);
    }
    mamba_scan<<<B_SZ * NHEADS, 256, 0, stream>>>(
        zx, conv_w, conv_b, R_x, R_B, R_C, R_dt, dt_bias, A_log, Dv, yz);
    {   // out-projection
        const int M = MROWS, N = DMODEL, K = DINNER;
        const int grid = (M / 128) * ((N + 63) / 64);
        gemm_nt_f32<<<grid, 256, 0, stream>>>(yz, W_out, out, M, N, K);
    }
}